// Round 1
// baseline (67.151 us; speedup 1.0000x reference)
//
#include <hip/hip_runtime.h>
#include <cstddef>

// Problem constants
#define NB 4
#define LQ 512
#define LK 512
#define QF 256
#define NH 128
#define VD 256

__device__ __forceinline__ float fexp2(float x) {
    float r; asm("v_exp_f32 %0, %1" : "=v"(r) : "v"(x)); return r;
}
__device__ __forceinline__ float frcp(float x) {
    float r; asm("v_rcp_f32 %0, %1" : "=v"(r) : "v"(x)); return r;
}

constexpr float kLog2e = 1.4426950408889634f;
constexpr float kPreScale = 2.0f * kLog2e;   // fold tanh's 2*log2(e) into the projections

// ---------------------------------------------------------------------------
// Kernel A: projections.  P[row][h] = kPreScale * sum_f In[row][f] * W[h][f]
// One block handles TI=16 rows of either queries (which=0) or keys (which=1).
// Row data staged in LDS (broadcast reads); W rows read per-thread from L2.
// ---------------------------------------------------------------------------
constexpr int TI = 16;

__global__ __launch_bounds__(256) void proj_kernel(
    const float* __restrict__ queries, const float* __restrict__ keys,
    const float* __restrict__ W_q, const float* __restrict__ W_k,
    float* __restrict__ qp, float* __restrict__ kp)
{
    const int tile  = blockIdx.x;      // 0 .. 2*(NB*LQ/TI)-1
    const int which = tile & 1;
    const int rt    = tile >> 1;       // row-tile index
    const float* In = which ? keys : queries;
    const float* W  = which ? W_k   : W_q;
    float*      Out = which ? kp    : qp;
    const int row0  = rt * TI;

    __shared__ float rows[TI][QF];

    const int t = threadIdx.x;         // 0..255
    // Stage TI*QF = 4096 floats = 1024 float4, coalesced.
    const float4* In4  = (const float4*)(In + (size_t)row0 * QF);
    float4*       rws4 = (float4*)&rows[0][0];
    #pragma unroll
    for (int r = 0; r < 4; ++r) rws4[t + 256 * r] = In4[t + 256 * r];
    __syncthreads();

    const int h  = t & 127;
    const int i0 = t >> 7;             // 0 or 1; thread covers rows i0, i0+2, ..., i0+14
    float acc[8];
    #pragma unroll
    for (int r = 0; r < 8; ++r) acc[r] = 0.f;

    const float4* W4 = (const float4*)(W + (size_t)h * QF);
    #pragma unroll 4
    for (int f4 = 0; f4 < QF / 4; ++f4) {
        const float4 w = W4[f4];
        #pragma unroll
        for (int r = 0; r < 8; ++r) {
            const float4 x = *(const float4*)&rows[i0 + 2 * r][f4 * 4];
            acc[r] += w.x * x.x + w.y * x.y + w.z * x.z + w.w * x.w;
        }
    }
    #pragma unroll
    for (int r = 0; r < 8; ++r)
        Out[(size_t)(row0 + i0 + 2 * r) * NH + h] = kPreScale * acc[r];
}

// ---------------------------------------------------------------------------
// Kernel B: fused scores + masked softmax + attn write + PV.
// One block per (b, tile of TQ=4 query rows); wave w owns query i0+w.
// Each lane owns j = lane + 64*jj for jj in 0..7.
// tanh(x) = 1 - 2*rcp(exp2(xs)+1) where xs = (q+k) pre-scaled by 2*log2e.
// ---------------------------------------------------------------------------
constexpr int TQ = 4;

__global__ __launch_bounds__(256) void attn_kernel(
    const float* __restrict__ qp, const float* __restrict__ kp,
    const float* __restrict__ values, const int* __restrict__ valid_lens,
    const float* __restrict__ W_v,
    float* __restrict__ out, float* __restrict__ attn_out)
{
    const int blk = blockIdx.x;              // NB * (LQ/TQ) = 512
    const int b   = blk >> 7;                // / (LQ/TQ=128)
    const int it  = blk & 127;
    const int i0  = it * TQ;

    __shared__ float q_lds[TQ][NH];
    __shared__ float wv[NH];
    __shared__ float attn_lds[TQ][LK];

    const int t = threadIdx.x;
    if (t < NH) wv[t] = W_v[t];
    {   // TQ*NH = 512 consecutive floats
        const float* qrow = qp + (size_t)(b * LQ + i0) * NH;
        ((float*)q_lds)[t]       = qrow[t];
        ((float*)q_lds)[t + 256] = qrow[t + 256];
    }
    __syncthreads();

    const int wid  = t >> 6;
    const int lane = t & 63;
    const int i    = i0 + wid;
    const int vl   = valid_lens[b];

    const float*  kbase = kp + (size_t)b * LK * NH;
    const float4* q4    = (const float4*)q_lds[wid];
    const float4* wv4   = (const float4*)wv;

    float s[8];
    #pragma unroll
    for (int jj = 0; jj < 8; ++jj) {
        if (jj * 64 >= vl) { s[jj] = 0.f; continue; }   // wave-uniform skip
        const int j = lane + 64 * jj;
        const float4* k4 = (const float4*)(kbase + (size_t)j * NH);
        float a0 = 0.f, a1 = 0.f, a2 = 0.f, a3 = 0.f;
        #pragma unroll 8
        for (int h4 = 0; h4 < NH / 4; ++h4) {
            const float4 kv = k4[h4];
            const float4 qv = q4[h4];
            const float4 w  = wv4[h4];
            // tanh via exp2; inputs pre-scaled by 2*log2e
            float e0 = fexp2(qv.x + kv.x);
            float e1 = fexp2(qv.y + kv.y);
            float e2 = fexp2(qv.z + kv.z);
            float e3 = fexp2(qv.w + kv.w);
            float t0 = __builtin_fmaf(-2.f, frcp(e0 + 1.f), 1.f);
            float t1 = __builtin_fmaf(-2.f, frcp(e1 + 1.f), 1.f);
            float t2 = __builtin_fmaf(-2.f, frcp(e2 + 1.f), 1.f);
            float t3 = __builtin_fmaf(-2.f, frcp(e3 + 1.f), 1.f);
            a0 = __builtin_fmaf(w.x, t0, a0);
            a1 = __builtin_fmaf(w.y, t1, a1);
            a2 = __builtin_fmaf(w.z, t2, a2);
            a3 = __builtin_fmaf(w.w, t3, a3);
        }
        s[jj] = (a0 + a1) + (a2 + a3);
    }

    // masked softmax over j (per wave = per query row)
    float m = -1e30f;
    #pragma unroll
    for (int jj = 0; jj < 8; ++jj) {
        const int j = lane + 64 * jj;
        if (j < vl) m = fmaxf(m, s[jj]);
    }
    #pragma unroll
    for (int off = 1; off < 64; off <<= 1)
        m = fmaxf(m, __shfl_xor(m, off, 64));

    float p[8];
    float sum = 0.f;
    #pragma unroll
    for (int jj = 0; jj < 8; ++jj) {
        const int j = lane + 64 * jj;
        const float e = (j < vl) ? fexp2((s[jj] - m) * kLog2e) : 0.f;
        p[jj] = e;
        sum  += e;
    }
    #pragma unroll
    for (int off = 1; off < 64; off <<= 1)
        sum += __shfl_xor(sum, off, 64);
    const float rs = frcp(sum);

    float* attn_row = attn_out + (size_t)(b * LQ + i) * LK;
    #pragma unroll
    for (int jj = 0; jj < 8; ++jj) {
        const float a = p[jj] * rs;
        attn_lds[wid][lane + 64 * jj] = a;
        attn_row[lane + 64 * jj]      = a;   // coalesced per wave
    }
    __syncthreads();

    // PV: thread t owns output column v=t; loop valid j only (attn==0 beyond)
    const float* vbase = values + (size_t)b * LK * VD;
    float oacc[TQ] = {0.f, 0.f, 0.f, 0.f};
    const int jmax = (vl + 3) & ~3;          // attn_lds is exactly 0 in [vl, jmax)
    for (int j = 0; j < jmax; j += 4) {
        const float v0 = vbase[(size_t)(j + 0) * VD + t];
        const float v1 = vbase[(size_t)(j + 1) * VD + t];
        const float v2 = vbase[(size_t)(j + 2) * VD + t];
        const float v3 = vbase[(size_t)(j + 3) * VD + t];
        #pragma unroll
        for (int ii = 0; ii < TQ; ++ii) {
            const float4 a = *(const float4*)&attn_lds[ii][j];
            oacc[ii] += a.x * v0 + a.y * v1 + a.z * v2 + a.w * v3;
        }
    }
    float* outrow = out + (size_t)(b * LQ + i0) * VD;
    #pragma unroll
    for (int ii = 0; ii < TQ; ++ii)
        outrow[(size_t)ii * VD + t] = oacc[ii];
}

// ---------------------------------------------------------------------------
extern "C" void kernel_launch(void* const* d_in, const int* in_sizes, int n_in,
                              void* d_out, int out_size, void* d_ws, size_t ws_size,
                              hipStream_t stream)
{
    const float* queries    = (const float*)d_in[0];
    const float* keys       = (const float*)d_in[1];
    const float* values     = (const float*)d_in[2];
    const int*   valid_lens = (const int*)  d_in[3];
    const float* W_q        = (const float*)d_in[4];
    const float* W_k        = (const float*)d_in[5];
    const float* W_v        = (const float*)d_in[6];

    float* out      = (float*)d_out;                       // [NB, LQ, VD]
    float* attn_out = out + (size_t)NB * LQ * VD;          // [NB, LQ, LK]

    float* qp = (float*)d_ws;                              // [NB, LQ, NH] pre-scaled
    float* kp = qp + (size_t)NB * LQ * NH;                 // [NB, LK, NH] pre-scaled

    const int proj_blocks = 2 * (NB * LQ / TI);            // 256
    proj_kernel<<<proj_blocks, 256, 0, stream>>>(queries, keys, W_q, W_k, qp, kp);

    const int attn_blocks = NB * (LQ / TQ);                // 512
    attn_kernel<<<attn_blocks, 256, 0, stream>>>(qp, kp, values, valid_lens, W_v,
                                                 out, attn_out);
}

// Round 2
// 60.453 us; speedup vs baseline: 1.1108x; 1.1108x over previous
//
#include <hip/hip_runtime.h>
#include <cstddef>

// Problem constants
#define NB 4
#define LQ 512
#define LK 512
#define QF 256
#define NH 128
#define VD 256

__device__ __forceinline__ float fexp2(float x) {
    float r; asm("v_exp_f32 %0, %1" : "=v"(r) : "v"(x)); return r;
}
__device__ __forceinline__ float frcp(float x) {
    float r; asm("v_rcp_f32 %0, %1" : "=v"(r) : "v"(x)); return r;
}

constexpr float kLog2e = 1.4426950408889634f;
constexpr float kPreScale = 2.0f * kLog2e;   // fold tanh's 2*log2(e) into the projections

// ---------------------------------------------------------------------------
// Kernel A: projections.  P[row][h] = kPreScale * sum_f In[row][f] * W[h][f]
// ---------------------------------------------------------------------------
constexpr int TI = 16;

__global__ __launch_bounds__(256) void proj_kernel(
    const float* __restrict__ queries, const float* __restrict__ keys,
    const float* __restrict__ W_q, const float* __restrict__ W_k,
    float* __restrict__ qp, float* __restrict__ kp)
{
    const int tile  = blockIdx.x;      // 0 .. 2*(NB*LQ/TI)-1
    const int which = tile & 1;
    const int rt    = tile >> 1;
    const float* In = which ? keys : queries;
    const float* W  = which ? W_k   : W_q;
    float*      Out = which ? kp    : qp;
    const int row0  = rt * TI;

    __shared__ float rows[TI][QF];

    const int t = threadIdx.x;
    const float4* In4  = (const float4*)(In + (size_t)row0 * QF);
    float4*       rws4 = (float4*)&rows[0][0];
    #pragma unroll
    for (int r = 0; r < 4; ++r) rws4[t + 256 * r] = In4[t + 256 * r];
    __syncthreads();

    const int h  = t & 127;
    const int i0 = t >> 7;
    float acc[8];
    #pragma unroll
    for (int r = 0; r < 8; ++r) acc[r] = 0.f;

    const float4* W4 = (const float4*)(W + (size_t)h * QF);
    #pragma unroll 4
    for (int f4 = 0; f4 < QF / 4; ++f4) {
        const float4 w = W4[f4];
        #pragma unroll
        for (int r = 0; r < 8; ++r) {
            const float4 x = *(const float4*)&rows[i0 + 2 * r][f4 * 4];
            acc[r] += w.x * x.x + w.y * x.y + w.z * x.z + w.w * x.w;
        }
    }
    #pragma unroll
    for (int r = 0; r < 8; ++r)
        Out[(size_t)(row0 + i0 + 2 * r) * NH + h] = kPreScale * acc[r];
}

// ---------------------------------------------------------------------------
// Kernel B: fused scores + masked softmax + attn write + PV.
// 1024 threads = 16 waves per block; TQ=4 queries per block.
// Wave w: query qi = w&3, j-slice group g = w>>2; owns slices jj = g, g+4
// (interleaved so any valid_len keeps all wave-groups balanced).
// Softmax: per-wave shfl reduce -> 16-entry LDS cross-wave combine.
// PV: thread t -> (j-quarter g2 = t>>8, column c = t&255); partial
// accumulators reduced through LDS. No redundant values reads.
// score = sumW - 2 * sum_h w[h]*rcp(exp2(qs+ks)+1)   (qs,ks pre-scaled)
// ---------------------------------------------------------------------------
constexpr int TQ = 4;

__global__ __launch_bounds__(1024, 8) void attn_kernel(
    const float* __restrict__ qp, const float* __restrict__ kp,
    const float* __restrict__ values, const int* __restrict__ valid_lens,
    const float* __restrict__ W_v,
    float* __restrict__ out, float* __restrict__ attn_out)
{
    const int blk = blockIdx.x;              // NB * (LQ/TQ) = 512
    const int b   = blk >> 7;
    const int i0  = (blk & 127) * TQ;

    __shared__ float q_lds[TQ][NH];
    __shared__ float wv[NH];
    __shared__ float attn_lds[TQ][LK];
    __shared__ float pacc[TQ][TQ][VD];       // [j-quarter][query][col]
    __shared__ float redm[16];
    __shared__ float reds[16];

    const int t = threadIdx.x;               // 0..1023
    if (t < NH) wv[t] = W_v[t];
    if (t < TQ * NH) {
        ((float*)q_lds)[t] = qp[(size_t)(b * LQ + i0) * NH + t];
    }
    __syncthreads();

    const int wid  = t >> 6;
    const int lane = t & 63;
    const int qi   = wid & 3;                // query within tile
    const int g    = wid >> 2;               // slice group 0..3
    const int vl   = valid_lens[b];

    const float4* q4    = (const float4*)q_lds[qi];
    const float4* wv4   = (const float4*)wv;
    const float*  kbase = kp + (size_t)b * LK * NH;

    // sumW = sum_h W_v[h]  (uniform broadcast LDS reads, once)
    float sumW = 0.f;
    #pragma unroll 8
    for (int h4 = 0; h4 < NH / 4; ++h4) {
        const float4 w = wv4[h4];
        sumW += (w.x + w.y) + (w.z + w.w);
    }

    // ---- scores: 2 slices per wave ----
    float s[2];
    #pragma unroll
    for (int u = 0; u < 2; ++u) {
        const int jj = g + 4 * u;
        s[u] = 0.f;
        if (jj * 64 < vl) {                  // wave-uniform
            const int j = lane + 64 * jj;
            const float4* k4 = (const float4*)(kbase + (size_t)j * NH);
            float a0 = 0.f, a1 = 0.f, a2 = 0.f, a3 = 0.f;
            #pragma unroll 4
            for (int h4 = 0; h4 < NH / 4; ++h4) {
                const float4 kv = k4[h4];
                const float4 qv = q4[h4];
                const float4 w  = wv4[h4];
                const float r0 = frcp(fexp2(qv.x + kv.x) + 1.f);
                const float r1 = frcp(fexp2(qv.y + kv.y) + 1.f);
                const float r2 = frcp(fexp2(qv.z + kv.z) + 1.f);
                const float r3 = frcp(fexp2(qv.w + kv.w) + 1.f);
                a0 = __builtin_fmaf(w.x, r0, a0);
                a1 = __builtin_fmaf(w.y, r1, a1);
                a2 = __builtin_fmaf(w.z, r2, a2);
                a3 = __builtin_fmaf(w.w, r3, a3);
            }
            s[u] = __builtin_fmaf(-2.f, (a0 + a1) + (a2 + a3), sumW);
        }
    }

    // ---- masked softmax (per query, across 4 waves) ----
    float m = -1e30f;
    #pragma unroll
    for (int u = 0; u < 2; ++u) {
        const int j = lane + 64 * (g + 4 * u);
        if (j < vl) m = fmaxf(m, s[u]);
    }
    #pragma unroll
    for (int off = 1; off < 64; off <<= 1)
        m = fmaxf(m, __shfl_xor(m, off, 64));
    if (lane == 0) redm[wid] = m;
    __syncthreads();
    m = fmaxf(fmaxf(redm[qi], redm[qi + 4]), fmaxf(redm[qi + 8], redm[qi + 12]));

    float p[2];
    float sum = 0.f;
    #pragma unroll
    for (int u = 0; u < 2; ++u) {
        const int j = lane + 64 * (g + 4 * u);
        const float e = (j < vl) ? fexp2((s[u] - m) * kLog2e) : 0.f;
        p[u] = e;
        sum += e;
    }
    #pragma unroll
    for (int off = 1; off < 64; off <<= 1)
        sum += __shfl_xor(sum, off, 64);
    if (lane == 0) reds[wid] = sum;
    __syncthreads();
    const float rs = frcp((reds[qi] + reds[qi + 4]) + (reds[qi + 8] + reds[qi + 12]));

    float* attn_row = attn_out + (size_t)(b * LQ + i0 + qi) * LK;
    #pragma unroll
    for (int u = 0; u < 2; ++u) {
        const int j = lane + 64 * (g + 4 * u);
        const float a = p[u] * rs;
        attn_lds[qi][j] = a;
        attn_row[j]     = a;                 // coalesced per wave
    }
    __syncthreads();

    // ---- PV: j split across 4 groups, partials reduced in LDS ----
    const int g2  = t >> 8;                  // j-quarter
    const int c   = t & 255;                 // value column
    const int vlr = (vl + 3) & ~3;           // attn_lds is exact 0 in [vl, LK)
    const int j0  = g2 * 128;
    const int j1  = min(j0 + 128, vlr);

    float acc[TQ] = {0.f, 0.f, 0.f, 0.f};
    const float* vcol = values + (size_t)b * LK * VD + c;
    for (int j = j0; j < j1; j += 4) {
        const float v0 = vcol[(size_t)(j + 0) * VD];
        const float v1 = vcol[(size_t)(j + 1) * VD];
        const float v2 = vcol[(size_t)(j + 2) * VD];
        const float v3 = vcol[(size_t)(j + 3) * VD];
        #pragma unroll
        for (int ii = 0; ii < TQ; ++ii) {
            const float4 a = *(const float4*)&attn_lds[ii][j];   // uniform broadcast
            acc[ii] += a.x * v0 + a.y * v1 + a.z * v2 + a.w * v3;
        }
    }
    #pragma unroll
    for (int ii = 0; ii < TQ; ++ii) pacc[g2][ii][c] = acc[ii];
    __syncthreads();

    {
        const int ii = t >> 8;
        const int cc = t & 255;
        out[(size_t)(b * LQ + i0 + ii) * VD + cc] =
            (pacc[0][ii][cc] + pacc[1][ii][cc]) + (pacc[2][ii][cc] + pacc[3][ii][cc]);
    }
}

// ---------------------------------------------------------------------------
extern "C" void kernel_launch(void* const* d_in, const int* in_sizes, int n_in,
                              void* d_out, int out_size, void* d_ws, size_t ws_size,
                              hipStream_t stream)
{
    const float* queries    = (const float*)d_in[0];
    const float* keys       = (const float*)d_in[1];
    const float* values     = (const float*)d_in[2];
    const int*   valid_lens = (const int*)  d_in[3];
    const float* W_q        = (const float*)d_in[4];
    const float* W_k        = (const float*)d_in[5];
    const float* W_v        = (const float*)d_in[6];

    float* out      = (float*)d_out;                       // [NB, LQ, VD]
    float* attn_out = out + (size_t)NB * LQ * VD;          // [NB, LQ, LK]

    float* qp = (float*)d_ws;                              // [NB, LQ, NH] pre-scaled
    float* kp = qp + (size_t)NB * LQ * NH;                 // [NB, LK, NH] pre-scaled

    const int proj_blocks = 2 * (NB * LQ / TI);            // 256
    proj_kernel<<<proj_blocks, 256, 0, stream>>>(queries, keys, W_q, W_k, qp, kp);

    const int attn_blocks = NB * (LQ / TQ);                // 512
    attn_kernel<<<attn_blocks, 1024, 0, stream>>>(qp, kp, values, valid_lens, W_v,
                                                  out, attn_out);
}

// Round 3
// 40.965 us; speedup vs baseline: 1.6392x; 1.4757x over previous
//
#include <hip/hip_runtime.h>
#include <cstddef>

// Problem constants
#define NB 4
#define LQ 512
#define LK 512
#define QF 256
#define NH 128
#define VD 256

__device__ __forceinline__ float fexp2(float x) {
    float r; asm("v_exp_f32 %0, %1" : "=v"(r) : "v"(x)); return r;
}
__device__ __forceinline__ float frcp(float x) {
    float r; asm("v_rcp_f32 %0, %1" : "=v"(r) : "v"(x)); return r;
}

constexpr float kLog2e    = 1.4426950408889634f;
constexpr float kPreScale = 2.0f * kLog2e;   // tanh(x) = 1 - 2/(1 + exp2(kPreScale*x))

// ---------------------------------------------------------------------------
// K1: projections + exponentials.
//   eq [b*LQ+i][h] = exp2(kPreScale * (Q·Wq^T))    row-major  [2048][128]
//   ekt[b][h][j]   = exp2(kPreScale * (K·Wk^T))    transposed [4][128][512]
// Then scores use exp2(ps*(q+k)) = Eq*Ek  -> one transcendental per element
// moved out of the O(LQ*LK*H) loop.
// Scatter fix vs R2: lanes span (4 rows x 16 h), so a W b128 load touches 16
// lines, not 64; per-thread A=4 row-accumulators amortize each W row.
// LDS rows padded to 260 floats: i0 lanes hit banks {c,c+4,c+8,c+12} (free).
// ---------------------------------------------------------------------------
constexpr int TI = 16;

__global__ __launch_bounds__(256) void proj_kernel(
    const float* __restrict__ queries, const float* __restrict__ keys,
    const float* __restrict__ W_q, const float* __restrict__ W_k,
    float* __restrict__ eq, float* __restrict__ ekt)
{
    const int id    = blockIdx.x;        // 512 = 2 which * 128 row-tiles * 2 h-tiles
    const int which = id & 1;
    const int rt    = (id >> 1) & 127;
    const int ht    = id >> 8;           // 0..1
    const float* In = which ? keys : queries;
    const float* W  = which ? W_k  : W_q;
    const int row0  = rt * TI;

    __shared__ float rows[TI][QF + 4];   // pad: stride 260 floats (16B aligned)

    const int t = threadIdx.x;
    {   // stage TI rows, coalesced (wave reads 1KB of one row per instr)
        const int f4 = t & 63;
        const int tr = t >> 6;
        const float4* In4 = (const float4*)In;
        #pragma unroll
        for (int k = 0; k < TI / 4; ++k) {
            const int r = tr + 4 * k;
            ((float4*)&rows[r][0])[f4] = In4[(size_t)(row0 + r) * 64 + f4];
        }
    }
    __syncthreads();

    const int i0 = t & 3;                // row lane
    const int h  = ht * 64 + (t >> 2);   // 16 h per wave -> 16 lines per W load
    float acc[4] = {0.f, 0.f, 0.f, 0.f};

    const float4* W4 = (const float4*)(W + (size_t)h * QF);
    #pragma unroll 4
    for (int f4 = 0; f4 < QF / 4; ++f4) {
        const float4 w = W4[f4];
        #pragma unroll
        for (int r = 0; r < 4; ++r) {
            const float4 x = *(const float4*)&rows[i0 + 4 * r][f4 * 4];
            acc[r] += w.x * x.x + w.y * x.y + w.z * x.z + w.w * x.w;
        }
    }

    if (which == 0) {
        #pragma unroll
        for (int r = 0; r < 4; ++r)
            eq[(size_t)(row0 + i0 + 4 * r) * NH + h] = fexp2(kPreScale * acc[r]);
    } else {
        #pragma unroll
        for (int r = 0; r < 4; ++r) {
            const int row = row0 + i0 + 4 * r;
            const int b   = row >> 9;
            const int rl  = row & 511;
            ekt[((size_t)b * NH + h) * LK + rl] = fexp2(kPreScale * acc[r]);
        }
    }
}

// ---------------------------------------------------------------------------
// K2: scores.  Block = one item (b, 8-query tile, 64-key chunk); 4 waves,
// each wave owns 2 queries sharing every Ek load.  Inactive chunks exit
// immediately.  Block-id swizzle interleaves (b, jc) so the ~8 blocks that
// land on one CU mix batches/chunks -> balanced despite valid_len spread.
//   score = sumW - 2 * sum_h w[h] * rcp(fma(Eq, Ek, 1))
// Scores are written into the attn region of d_out (K3 overwrites in place).
// ---------------------------------------------------------------------------
__global__ __launch_bounds__(256, 8) void score_kernel(
    const float* __restrict__ eq, const float* __restrict__ ekt,
    const int* __restrict__ valid_lens, const float* __restrict__ W_v,
    float* __restrict__ scores)
{
    const int id  = blockIdx.x;          // 2048 = 64 it * (4 b * 8 jc)
    const int it  = id & 63;
    const int bjc = id >> 6;
    const int b   = bjc >> 3;
    const int jc  = bjc & 7;
    const int vl  = valid_lens[b];
    if (jc * 64 >= vl) return;           // uniform early exit

    __shared__ float q_lds[8][NH];
    __shared__ float wv[NH];

    const int t  = threadIdx.x;
    const int i0 = it * 8;
    #pragma unroll
    for (int r = 0; r < 4; ++r)
        ((float*)q_lds)[t + 256 * r] = eq[(size_t)(b * LQ + i0) * NH + t + 256 * r];
    if (t < NH) wv[t] = W_v[t];
    __syncthreads();

    const int wid  = t >> 6;
    const int lane = t & 63;
    const float4* qa4 = (const float4*)q_lds[2 * wid];
    const float4* qb4 = (const float4*)q_lds[2 * wid + 1];
    const float4* wv4 = (const float4*)wv;

    float sumW = 0.f;
    #pragma unroll 8
    for (int h4 = 0; h4 < NH / 4; ++h4) {
        const float4 w = wv4[h4];
        sumW += (w.x + w.y) + (w.z + w.w);
    }

    const float* p = ekt + (size_t)b * NH * LK + jc * 64 + lane;
    float aA0 = 0.f, aA1 = 0.f, aA2 = 0.f, aA3 = 0.f;
    float aB0 = 0.f, aB1 = 0.f, aB2 = 0.f, aB3 = 0.f;
    #pragma unroll 4
    for (int h4 = 0; h4 < NH / 4; ++h4) {
        const float e0 = p[(size_t)(4 * h4 + 0) * LK];   // coalesced 256B
        const float e1 = p[(size_t)(4 * h4 + 1) * LK];
        const float e2 = p[(size_t)(4 * h4 + 2) * LK];
        const float e3 = p[(size_t)(4 * h4 + 3) * LK];
        const float4 w  = wv4[h4];
        const float4 qa = qa4[h4];
        const float4 qb = qb4[h4];
        aA0 = __builtin_fmaf(w.x, frcp(__builtin_fmaf(qa.x, e0, 1.f)), aA0);
        aA1 = __builtin_fmaf(w.y, frcp(__builtin_fmaf(qa.y, e1, 1.f)), aA1);
        aA2 = __builtin_fmaf(w.z, frcp(__builtin_fmaf(qa.z, e2, 1.f)), aA2);
        aA3 = __builtin_fmaf(w.w, frcp(__builtin_fmaf(qa.w, e3, 1.f)), aA3);
        aB0 = __builtin_fmaf(w.x, frcp(__builtin_fmaf(qb.x, e0, 1.f)), aB0);
        aB1 = __builtin_fmaf(w.y, frcp(__builtin_fmaf(qb.y, e1, 1.f)), aB1);
        aB2 = __builtin_fmaf(w.z, frcp(__builtin_fmaf(qb.z, e2, 1.f)), aB2);
        aB3 = __builtin_fmaf(w.w, frcp(__builtin_fmaf(qb.w, e3, 1.f)), aB3);
    }
    const float sA = __builtin_fmaf(-2.f, (aA0 + aA1) + (aA2 + aA3), sumW);
    const float sB = __builtin_fmaf(-2.f, (aB0 + aB1) + (aB2 + aB3), sumW);

    const int ra = i0 + 2 * wid;
    scores[((size_t)b * LQ + ra)     * LK + jc * 64 + lane] = sA;
    scores[((size_t)b * LQ + ra + 1) * LK + jc * 64 + lane] = sB;
}

// ---------------------------------------------------------------------------
// K3: masked softmax + attn write + PV.  Same structure as R2's attn kernel,
// with the score phase replaced by a coalesced load from the attn region
// (each wave reads only its own slices before overwriting them -> in-place
// is race-free: rows never shared across blocks, slices never across waves).
// ---------------------------------------------------------------------------
constexpr int TQ = 4;

__global__ __launch_bounds__(1024, 8) void smpv_kernel(
    const float* __restrict__ values, const int* __restrict__ valid_lens,
    float* __restrict__ out, float* __restrict__ attn_out /* = scores in */)
{
    const int blk = blockIdx.x;              // NB * (LQ/TQ) = 512
    const int b   = blk >> 7;
    const int i0  = (blk & 127) * TQ;

    __shared__ float attn_lds[TQ][LK];
    __shared__ float pacc[TQ][TQ][VD];
    __shared__ float redm[16];
    __shared__ float reds[16];

    const int t    = threadIdx.x;
    const int wid  = t >> 6;
    const int lane = t & 63;
    const int qi   = wid & 3;
    const int g    = wid >> 2;
    const int i    = i0 + qi;
    const int vl   = valid_lens[b];

    const float* srow = attn_out + (size_t)(b * LQ + i) * LK;
    float s[2];
    #pragma unroll
    for (int u = 0; u < 2; ++u) {
        const int jj = g + 4 * u;
        s[u] = 0.f;
        if (jj * 64 < vl) s[u] = srow[jj * 64 + lane];   // written by K2
    }

    // masked softmax (per query, 4 waves)
    float m = -1e30f;
    #pragma unroll
    for (int u = 0; u < 2; ++u) {
        const int j = lane + 64 * (g + 4 * u);
        if (j < vl) m = fmaxf(m, s[u]);
    }
    #pragma unroll
    for (int off = 1; off < 64; off <<= 1)
        m = fmaxf(m, __shfl_xor(m, off, 64));
    if (lane == 0) redm[wid] = m;
    __syncthreads();
    m = fmaxf(fmaxf(redm[qi], redm[qi + 4]), fmaxf(redm[qi + 8], redm[qi + 12]));

    float p[2];
    float sum = 0.f;
    #pragma unroll
    for (int u = 0; u < 2; ++u) {
        const int j = lane + 64 * (g + 4 * u);
        const float e = (j < vl) ? fexp2((s[u] - m) * kLog2e) : 0.f;
        p[u] = e;
        sum += e;
    }
    #pragma unroll
    for (int off = 1; off < 64; off <<= 1)
        sum += __shfl_xor(sum, off, 64);
    if (lane == 0) reds[wid] = sum;
    __syncthreads();
    const float rs = frcp((reds[qi] + reds[qi + 4]) + (reds[qi + 8] + reds[qi + 12]));

    float* attn_row = attn_out + (size_t)(b * LQ + i) * LK;
    #pragma unroll
    for (int u = 0; u < 2; ++u) {
        const int j = lane + 64 * (g + 4 * u);
        const float a = p[u] * rs;
        attn_lds[qi][j] = a;
        attn_row[j]     = a;                 // overwrite scores with attn
    }
    __syncthreads();

    // PV: j split across 4 thread-groups, partials reduced in LDS
    const int g2  = t >> 8;
    const int c   = t & 255;
    const int vlr = (vl + 3) & ~3;           // attn_lds exact 0 in [vl, LK)
    const int j0  = g2 * 128;
    const int j1  = min(j0 + 128, vlr);

    float acc[TQ] = {0.f, 0.f, 0.f, 0.f};
    const float* vcol = values + (size_t)b * LK * VD + c;
    for (int j = j0; j < j1; j += 4) {
        const float v0 = vcol[(size_t)(j + 0) * VD];
        const float v1 = vcol[(size_t)(j + 1) * VD];
        const float v2 = vcol[(size_t)(j + 2) * VD];
        const float v3 = vcol[(size_t)(j + 3) * VD];
        #pragma unroll
        for (int ii = 0; ii < TQ; ++ii) {
            const float4 a = *(const float4*)&attn_lds[ii][j];
            acc[ii] += a.x * v0 + a.y * v1 + a.z * v2 + a.w * v3;
        }
    }
    #pragma unroll
    for (int ii = 0; ii < TQ; ++ii) pacc[g2][ii][c] = acc[ii];
    __syncthreads();

    {
        const int ii = t >> 8;
        const int cc = t & 255;
        out[(size_t)(b * LQ + i0 + ii) * VD + cc] =
            (pacc[0][ii][cc] + pacc[1][ii][cc]) + (pacc[2][ii][cc] + pacc[3][ii][cc]);
    }
}

// ---------------------------------------------------------------------------
extern "C" void kernel_launch(void* const* d_in, const int* in_sizes, int n_in,
                              void* d_out, int out_size, void* d_ws, size_t ws_size,
                              hipStream_t stream)
{
    const float* queries    = (const float*)d_in[0];
    const float* keys       = (const float*)d_in[1];
    const float* values     = (const float*)d_in[2];
    const int*   valid_lens = (const int*)  d_in[3];
    const float* W_q        = (const float*)d_in[4];
    const float* W_k        = (const float*)d_in[5];
    const float* W_v        = (const float*)d_in[6];

    float* out      = (float*)d_out;                       // [NB, LQ, VD]
    float* attn_out = out + (size_t)NB * LQ * VD;          // [NB, LQ, LK]

    float* eq  = (float*)d_ws;                             // [NB*LQ][NH]  exp2-projections
    float* ekt = eq + (size_t)NB * LQ * NH;                // [NB][NH][LK] transposed

    proj_kernel <<<512, 256, 0, stream>>>(queries, keys, W_q, W_k, eq, ekt);
    score_kernel<<<2048, 256, 0, stream>>>(eq, ekt, valid_lens, W_v, attn_out);
    smpv_kernel <<<NB * (LQ / TQ), 1024, 0, stream>>>(values, valid_lens, out, attn_out);
}